// Round 3
// baseline (289.112 us; speedup 1.0000x reference)
//
#include <hip/hip_runtime.h>
#include <stdint.h>

typedef __bf16 bf16;
typedef __bf16 bf16x8 __attribute__((ext_vector_type(8)));
typedef __bf16 bf16x4 __attribute__((ext_vector_type(4)));
typedef float f32x4 __attribute__((ext_vector_type(4)));

#define LQ    16384   // B*L total rows
#define CDIM  1024
#define DDIM  128
#define SCALE 0.08838834764831845f  // 1/sqrt(128)

// ---------------- K0: transpose + downcast weights W[k][n] -> Wt[n][k] --
__global__ void wtrans_kernel(const float* __restrict__ Wq, const float* __restrict__ Wk,
                              const float* __restrict__ Wv, bf16* __restrict__ Wt3) {
  int idx = blockIdx.x * 256 + threadIdx.x;      // 0 .. 3*131072
  int y = idx >> 17;
  int rem = idx & 131071;
  int k = rem >> 7, n = rem & 127;
  const float* W = (y == 0) ? Wq : (y == 1) ? Wk : Wv;
  Wt3[(size_t)y * 131072 + (size_t)n * CDIM + k] = (bf16)W[rem];
}

// ---------------- K1: QKV projection GEMM ------------------------------
// grid (128 m-tiles, 3 proj). Tile 128x128, BK=64. x is fp32 (converted to
// bf16 during staging); weights pre-transposed bf16. y=2 writes V transposed.
__global__ __launch_bounds__(256, 2) void qkv_gemm(
    const float* __restrict__ x, const bf16* __restrict__ Wt3,
    const float* __restrict__ bq, const float* __restrict__ bk, const float* __restrict__ bv,
    bf16* __restrict__ Qw, bf16* __restrict__ Kw, bf16* __restrict__ Vtw) {
  __shared__ bf16 Al[128 * 64];   // [m][k]
  __shared__ bf16 Bl[128 * 64];   // [n][k]  (from transposed weights)
  const int t = threadIdx.x;
  const int w = t >> 6;
  const int lane = t & 63;
  const int l15 = lane & 15;
  const int quad = lane >> 4;
  const int y = blockIdx.y;
  const int m0 = blockIdx.x * 128;
  const bf16* W = Wt3 + (size_t)y * (DDIM * CDIM);
  const float* bias = (y == 0) ? bq : (y == 1) ? bk : bv;
  const int m_off = (w & 1) * 64;
  const int n_off = (w >> 1) * 64;
  const int sr = t >> 3;          // 0..31 staging row-within-group
  const int sc = (t & 7) << 3;    // staging col (8-elem chunk)

  f32x4 zero4 = {0.f, 0.f, 0.f, 0.f};
  f32x4 acc[4][4];
#pragma unroll
  for (int i = 0; i < 4; i++)
#pragma unroll
    for (int j = 0; j < 4; j++) acc[i][j] = zero4;

  for (int k0 = 0; k0 < CDIM; k0 += 64) {
    __syncthreads();
    // x: fp32 -> bf16 conversion in-flight. 128 rows x 64 cols = 2048 float4s.
    float4 xa[8];
#pragma unroll
    for (int c = 0; c < 8; c++) {
      int idx = c * 256 + t;
      int row = idx >> 4;             // 0..127
      int col = (idx & 15) << 2;      // 0..60
      xa[c] = *(const float4*)&x[(size_t)(m0 + row) * CDIM + k0 + col];
    }
    bf16x8 wa[4];
#pragma unroll
    for (int c = 0; c < 4; c++)
      wa[c] = *(const bf16x8*)&W[(size_t)(c * 32 + sr) * CDIM + k0 + sc];
#pragma unroll
    for (int c = 0; c < 8; c++) {
      int idx = c * 256 + t;
      int row = idx >> 4;
      int col = (idx & 15) << 2;
      bf16x4 v;
      v[0] = (bf16)xa[c].x; v[1] = (bf16)xa[c].y;
      v[2] = (bf16)xa[c].z; v[3] = (bf16)xa[c].w;
      *(bf16x4*)&Al[row * 64 + col] = v;
    }
#pragma unroll
    for (int c = 0; c < 4; c++)
      *(bf16x8*)&Bl[(c * 32 + sr) * 64 + sc] = wa[c];
    __syncthreads();
#pragma unroll
    for (int ks = 0; ks < 2; ks++) {
      bf16x8 af[4], bfr[4];
#pragma unroll
      for (int mt = 0; mt < 4; mt++)
        af[mt] = *(const bf16x8*)&Al[(m_off + mt * 16 + l15) * 64 + ks * 32 + quad * 8];
#pragma unroll
      for (int nt = 0; nt < 4; nt++)
        bfr[nt] = *(const bf16x8*)&Bl[(n_off + nt * 16 + l15) * 64 + ks * 32 + quad * 8];
#pragma unroll
      for (int mt = 0; mt < 4; mt++)
#pragma unroll
        for (int nt = 0; nt < 4; nt++)
          acc[mt][nt] = __builtin_amdgcn_mfma_f32_16x16x32_bf16(af[mt], bfr[nt], acc[mt][nt], 0, 0, 0);
    }
  }

  float bias4[4];
#pragma unroll
  for (int nt = 0; nt < 4; nt++) bias4[nt] = bias[n_off + nt * 16 + l15];

  if (y < 2) {
    bf16* out = (y == 0) ? Qw : Kw;
#pragma unroll
    for (int mt = 0; mt < 4; mt++)
#pragma unroll
      for (int nt = 0; nt < 4; nt++) {
        int n = n_off + nt * 16 + l15;
#pragma unroll
        for (int r = 0; r < 4; r++) {
          int m = m0 + m_off + mt * 16 + quad * 4 + r;
          out[(size_t)m * DDIM + n] = (bf16)(acc[mt][nt][r] + bias4[nt]);
        }
      }
  } else {
#pragma unroll
    for (int mt = 0; mt < 4; mt++)
#pragma unroll
      for (int nt = 0; nt < 4; nt++) {
        int n = n_off + nt * 16 + l15;
        int m = m0 + m_off + mt * 16 + quad * 4;  // 4 consecutive q rows
        bf16x4 pv;
#pragma unroll
        for (int r = 0; r < 4; r++) pv[r] = (bf16)(acc[mt][nt][r] + bias4[nt]);
        *(bf16x4*)&Vtw[(size_t)n * LQ + m] = pv;
      }
  }
}

// ---------------- K2: flash attention ----------------------------------
// grid (128 q-blocks of 128 rows, 2 KV halves). 256 thr; wave w owns 32 q rows.
// Writes unnormalized O (fp32) + per-row (m,l) partials.
__global__ __launch_bounds__(256, 1) void flash_kernel(
    const bf16* __restrict__ Qw, const bf16* __restrict__ Kw, const bf16* __restrict__ Vtw,
    float* __restrict__ Op, float2* __restrict__ ml) {
  __shared__ bf16 Kl[64 * 128];       // [kv][d]
  __shared__ bf16 Vl[128 * 64];       // [d][kv]
  __shared__ bf16 Pl[4 * 32 * 72];    // per-wave [32][72] (pad 64->72)

  const int t = threadIdx.x;
  const int w = t >> 6;
  const int lane = t & 63;
  const int l15 = lane & 15;
  const int quad = lane >> 4;
  const int qb = blockIdx.x;          // 0..127
  const int s = blockIdx.y;           // 0..1
  const int batch = qb >> 5;
  const int q0w = qb * 128 + w * 32;
  const int kv_base = batch * 4096 + s * 2048;

  // Q fragments in registers: A[m=q][k=d]
  bf16x8 qf[2][4];
#pragma unroll
  for (int mt = 0; mt < 2; mt++)
#pragma unroll
    for (int ks = 0; ks < 4; ks++)
      qf[mt][ks] = *(const bf16x8*)&Qw[(size_t)(q0w + mt * 16 + l15) * DDIM + ks * 32 + quad * 8];

  f32x4 zero4 = {0.f, 0.f, 0.f, 0.f};
  f32x4 o[2][8];
#pragma unroll
  for (int mt = 0; mt < 2; mt++)
#pragma unroll
    for (int dt = 0; dt < 8; dt++) o[mt][dt] = zero4;
  float mi[2][4], li[2][4];
#pragma unroll
  for (int mt = 0; mt < 2; mt++)
#pragma unroll
    for (int r = 0; r < 4; r++) { mi[mt][r] = -INFINITY; li[mt][r] = 0.f; }

  bf16* Pw = Pl + w * (32 * 72);

  for (int tile = 0; tile < 32; tile++) {
    const int kv0 = kv_base + tile * 64;
    __syncthreads();
    {
      bf16x8 ka[4], va[4];
#pragma unroll
      for (int c = 0; c < 4; c++)
        ka[c] = *(const bf16x8*)&Kw[(size_t)(kv0 + c * 16 + (t >> 4)) * DDIM + ((t & 15) << 3)];
#pragma unroll
      for (int c = 0; c < 4; c++)
        va[c] = *(const bf16x8*)&Vtw[(size_t)(c * 32 + (t >> 3)) * LQ + kv0 + ((t & 7) << 3)];
#pragma unroll
      for (int c = 0; c < 4; c++)
        *(bf16x8*)&Kl[(c * 16 + (t >> 4)) * 128 + ((t & 15) << 3)] = ka[c];
#pragma unroll
      for (int c = 0; c < 4; c++)
        *(bf16x8*)&Vl[(c * 32 + (t >> 3)) * 64 + ((t & 7) << 3)] = va[c];
    }
    __syncthreads();

    // S = Q K^T  (m=q 32, n=kv 64)
    f32x4 sv[2][4];
#pragma unroll
    for (int mt = 0; mt < 2; mt++)
#pragma unroll
      for (int nt = 0; nt < 4; nt++) sv[mt][nt] = zero4;
#pragma unroll
    for (int ks = 0; ks < 4; ks++) {
      bf16x8 kf[4];
#pragma unroll
      for (int nt = 0; nt < 4; nt++)
        kf[nt] = *(const bf16x8*)&Kl[(nt * 16 + l15) * 128 + ks * 32 + quad * 8];
#pragma unroll
      for (int mt = 0; mt < 2; mt++)
#pragma unroll
        for (int nt = 0; nt < 4; nt++)
          sv[mt][nt] = __builtin_amdgcn_mfma_f32_16x16x32_bf16(qf[mt][ks], kf[nt], sv[mt][nt], 0, 0, 0);
    }
#pragma unroll
    for (int mt = 0; mt < 2; mt++)
#pragma unroll
      for (int nt = 0; nt < 4; nt++) sv[mt][nt] *= SCALE;

    // online softmax; C-layout: row q = mt*16 + quad*4 + r, col kv = nt*16 + l15
#pragma unroll
    for (int mt = 0; mt < 2; mt++) {
#pragma unroll
      for (int r = 0; r < 4; r++) {
        float rm = fmaxf(fmaxf(sv[mt][0][r], sv[mt][1][r]), fmaxf(sv[mt][2][r], sv[mt][3][r]));
#pragma unroll
        for (int msk = 1; msk < 16; msk <<= 1) rm = fmaxf(rm, __shfl_xor(rm, msk));
        float mnew = fmaxf(mi[mt][r], rm);
        float alpha = __expf(mi[mt][r] - mnew);
        mi[mt][r] = mnew;
        float rsum = 0.f;
#pragma unroll
        for (int nt = 0; nt < 4; nt++) {
          float p = __expf(sv[mt][nt][r] - mnew);
          sv[mt][nt][r] = p;
          rsum += p;
        }
#pragma unroll
        for (int msk = 1; msk < 16; msk <<= 1) rsum += __shfl_xor(rsum, msk);
        li[mt][r] = li[mt][r] * alpha + rsum;
#pragma unroll
        for (int dt = 0; dt < 8; dt++) o[mt][dt][r] *= alpha;   // per-row rescale
      }
    }

    // P: C-layout -> A-layout via own-wave LDS region (no barrier needed)
#pragma unroll
    for (int mt = 0; mt < 2; mt++)
#pragma unroll
      for (int nt = 0; nt < 4; nt++)
#pragma unroll
        for (int r = 0; r < 4; r++)
          Pw[(mt * 16 + quad * 4 + r) * 72 + nt * 16 + l15] = (bf16)sv[mt][nt][r];

    // O += P V   (A = P[m=q][k=kv], B = V[k=kv][n=d] from Vt)
#pragma unroll
    for (int ks = 0; ks < 2; ks++) {
      bf16x8 pf[2];
#pragma unroll
      for (int mt = 0; mt < 2; mt++)
        pf[mt] = *(const bf16x8*)&Pw[(mt * 16 + l15) * 72 + ks * 32 + quad * 8];
#pragma unroll
      for (int dt = 0; dt < 8; dt++) {
        bf16x8 vf = *(const bf16x8*)&Vl[(dt * 16 + l15) * 64 + ks * 32 + quad * 8];
#pragma unroll
        for (int mt = 0; mt < 2; mt++)
          o[mt][dt] = __builtin_amdgcn_mfma_f32_16x16x32_bf16(pf[mt], vf, o[mt][dt], 0, 0, 0);
      }
    }
  }

  // epilogue: unnormalized O + (m,l)
  const size_t po = (size_t)s * LQ * DDIM;
#pragma unroll
  for (int mt = 0; mt < 2; mt++)
#pragma unroll
    for (int dt = 0; dt < 8; dt++)
#pragma unroll
      for (int r = 0; r < 4; r++)
        Op[po + (size_t)(q0w + mt * 16 + quad * 4 + r) * DDIM + dt * 16 + l15] = o[mt][dt][r];
  if (l15 == 0) {
#pragma unroll
    for (int mt = 0; mt < 2; mt++)
#pragma unroll
      for (int r = 0; r < 4; r++)
        ml[(size_t)s * LQ + q0w + mt * 16 + quad * 4 + r] = make_float2(mi[mt][r], li[mt][r]);
  }
}

// ---------------- K3: combine the two KV-half partials (fp32 out) -------
__global__ void combine_kernel(const float* __restrict__ Op, const float2* __restrict__ ml,
                               float* __restrict__ out) {
  int idx = blockIdx.x * 256 + threadIdx.x;   // LQ * 32
  int q = idx >> 5;
  int d = (idx & 31) * 4;
  float2 a = ml[q];
  float2 b = ml[LQ + q];
  float M = fmaxf(a.x, b.x);
  float w0 = __expf(a.x - M), w1 = __expf(b.x - M);
  float inv = 1.0f / (a.y * w0 + b.y * w1);
  const float4 o0 = *(const float4*)&Op[(size_t)q * DDIM + d];
  const float4 o1 = *(const float4*)&Op[(size_t)LQ * DDIM + (size_t)q * DDIM + d];
  float4 r;
  r.x = (o0.x * w0 + o1.x * w1) * inv;
  r.y = (o0.y * w0 + o1.y * w1) * inv;
  r.z = (o0.z * w0 + o1.z * w1) * inv;
  r.w = (o0.w * w0 + o1.w * w1) * inv;
  *(float4*)&out[(size_t)q * DDIM + d] = r;
}

extern "C" void kernel_launch(void* const* d_in, const int* in_sizes, int n_in,
                              void* d_out, int out_size, void* d_ws, size_t ws_size,
                              hipStream_t stream) {
  const float* x  = (const float*)d_in[0];
  const float* Wq = (const float*)d_in[1];
  const float* bq = (const float*)d_in[2];
  const float* Wk = (const float*)d_in[3];
  const float* bk = (const float*)d_in[4];
  const float* Wv = (const float*)d_in[5];
  const float* bv = (const float*)d_in[6];
  char* ws = (char*)d_ws;
  bf16* Qw  = (bf16*)(ws);                       // 4 MB
  bf16* Kw  = (bf16*)(ws + ((size_t)4 << 20));   // 4 MB
  bf16* Vtw = (bf16*)(ws + ((size_t)8 << 20));   // 4 MB (transposed: [d][q])
  bf16* Wt3 = (bf16*)(ws + ((size_t)12 << 20));  // 768 KB
  float*  Op  = (float*)(ws + ((size_t)13 << 20)); // 16 MB
  float2* mlp = (float2*)(ws + ((size_t)29 << 20)); // 256 KB
  float* out = (float*)d_out;

  wtrans_kernel<<<1536, 256, 0, stream>>>(Wq, Wk, Wv, Wt3);
  qkv_gemm<<<dim3(128, 3), 256, 0, stream>>>(x, Wt3, bq, bk, bv, Qw, Kw, Vtw);
  flash_kernel<<<dim3(128, 2), 256, 0, stream>>>(Qw, Kw, Vtw, Op, mlp);
  combine_kernel<<<2048, 256, 0, stream>>>(Op, mlp, out);
}

// Round 4
// 200.148 us; speedup vs baseline: 1.4445x; 1.4445x over previous
//
#include <hip/hip_runtime.h>
#include <stdint.h>

typedef __bf16 bf16;
typedef __bf16 bf16x8 __attribute__((ext_vector_type(8)));
typedef __bf16 bf16x4 __attribute__((ext_vector_type(4)));
typedef float f32x4 __attribute__((ext_vector_type(4)));

#define LQ    16384   // B*L total rows
#define CDIM  1024
#define DDIM  128
#define NSPLIT 4
#define SCALE 0.08838834764831845f  // 1/sqrt(128)

// ---------------- K0: transpose + downcast weights W[k][n] -> Wt[n][k] --
__global__ void wtrans_kernel(const float* __restrict__ Wq, const float* __restrict__ Wk,
                              const float* __restrict__ Wv, bf16* __restrict__ Wt3) {
  int idx = blockIdx.x * 256 + threadIdx.x;      // 0 .. 3*131072
  int y = idx >> 17;
  int rem = idx & 131071;
  int k = rem >> 7, n = rem & 127;
  const float* W = (y == 0) ? Wq : (y == 1) ? Wk : Wv;
  Wt3[(size_t)y * 131072 + (size_t)n * CDIM + k] = (bf16)W[rem];
}

// ---------------- K1: QKV projection GEMM ------------------------------
// grid (256 m-tiles of 64 rows, 3 proj). Tile 64x128, BK=64, reg-prefetch.
__global__ __launch_bounds__(256, 3) void qkv_gemm(
    const float* __restrict__ x, const bf16* __restrict__ Wt3,
    const float* __restrict__ bq, const float* __restrict__ bk, const float* __restrict__ bv,
    bf16* __restrict__ Qw, bf16* __restrict__ Kw, bf16* __restrict__ Vtw) {
  __shared__ bf16 Al[64 * 72];    // [m][k] pad 64->72
  __shared__ bf16 Bl[128 * 72];   // [n][k] pad
  const int t = threadIdx.x;
  const int w = t >> 6;
  const int lane = t & 63;
  const int l15 = lane & 15;
  const int quad = lane >> 4;
  const int y = blockIdx.y;
  const int m0 = blockIdx.x * 64;
  const bf16* W = Wt3 + (size_t)y * (DDIM * CDIM);
  const float* bias = (y == 0) ? bq : (y == 1) ? bk : bv;
  const int m_off = (w & 1) * 32;
  const int n_off = (w >> 1) * 64;
  const int xr = t >> 4;          // x staging row 0..15 (x4 groups)
  const int xc = (t & 15) << 2;   // x staging col
  const int wr = t >> 3;          // W staging row 0..31 (x4 groups)
  const int wc = (t & 7) << 3;    // W staging col

  f32x4 zero4 = {0.f, 0.f, 0.f, 0.f};
  f32x4 acc[2][4];
#pragma unroll
  for (int i = 0; i < 2; i++)
#pragma unroll
    for (int j = 0; j < 4; j++) acc[i][j] = zero4;

  float4 xa[4];
  bf16x8 wa[4];
#pragma unroll
  for (int c = 0; c < 4; c++)
    xa[c] = *(const float4*)&x[(size_t)(m0 + c * 16 + xr) * CDIM + xc];
#pragma unroll
  for (int c = 0; c < 4; c++)
    wa[c] = *(const bf16x8*)&W[(size_t)(c * 32 + wr) * CDIM + wc];

  for (int kc = 0; kc < 16; kc++) {
    __syncthreads();
#pragma unroll
    for (int c = 0; c < 4; c++) {
      bf16x4 v;
      v[0] = (bf16)xa[c].x; v[1] = (bf16)xa[c].y;
      v[2] = (bf16)xa[c].z; v[3] = (bf16)xa[c].w;
      *(bf16x4*)&Al[(c * 16 + xr) * 72 + xc] = v;
    }
#pragma unroll
    for (int c = 0; c < 4; c++)
      *(bf16x8*)&Bl[(c * 32 + wr) * 72 + wc] = wa[c];
    __syncthreads();

    const int kn = (kc < 15 ? kc + 1 : 15) * 64;   // clamped prefetch
#pragma unroll
    for (int c = 0; c < 4; c++)
      xa[c] = *(const float4*)&x[(size_t)(m0 + c * 16 + xr) * CDIM + kn + xc];
#pragma unroll
    for (int c = 0; c < 4; c++)
      wa[c] = *(const bf16x8*)&W[(size_t)(c * 32 + wr) * CDIM + kn + wc];

#pragma unroll
    for (int ks = 0; ks < 2; ks++) {
      bf16x8 af[2], bfr[4];
#pragma unroll
      for (int mt = 0; mt < 2; mt++)
        af[mt] = *(const bf16x8*)&Al[(m_off + mt * 16 + l15) * 72 + ks * 32 + quad * 8];
#pragma unroll
      for (int nt = 0; nt < 4; nt++)
        bfr[nt] = *(const bf16x8*)&Bl[(n_off + nt * 16 + l15) * 72 + ks * 32 + quad * 8];
#pragma unroll
      for (int mt = 0; mt < 2; mt++)
#pragma unroll
        for (int nt = 0; nt < 4; nt++)
          acc[mt][nt] = __builtin_amdgcn_mfma_f32_16x16x32_bf16(af[mt], bfr[nt], acc[mt][nt], 0, 0, 0);
    }
  }

  float bias4[4];
#pragma unroll
  for (int nt = 0; nt < 4; nt++) bias4[nt] = bias[n_off + nt * 16 + l15];

  if (y < 2) {
    bf16* out = (y == 0) ? Qw : Kw;
#pragma unroll
    for (int mt = 0; mt < 2; mt++)
#pragma unroll
      for (int nt = 0; nt < 4; nt++) {
        int n = n_off + nt * 16 + l15;
#pragma unroll
        for (int r = 0; r < 4; r++) {
          int m = m0 + m_off + mt * 16 + quad * 4 + r;
          out[(size_t)m * DDIM + n] = (bf16)(acc[mt][nt][r] + bias4[nt]);
        }
      }
  } else {
#pragma unroll
    for (int mt = 0; mt < 2; mt++)
#pragma unroll
      for (int nt = 0; nt < 4; nt++) {
        int n = n_off + nt * 16 + l15;
        int m = m0 + m_off + mt * 16 + quad * 4;  // 4 consecutive q rows
        bf16x4 pv;
#pragma unroll
        for (int r = 0; r < 4; r++) pv[r] = (bf16)(acc[mt][nt][r] + bias4[nt]);
        *(bf16x4*)&Vtw[(size_t)n * LQ + m] = pv;
      }
  }
}

// ---------------- K2: flash attention ----------------------------------
// grid (128 q-blocks of 128 rows, 4 KV quarters). 256 thr; wave owns 32 q rows.
// Padded LDS (conflict-free frag reads), reg-prefetch of next K/V tile.
// Writes unnormalized O (bf16) + per-row (m,l).
__global__ __launch_bounds__(256, 2) void flash_kernel(
    const bf16* __restrict__ Qw, const bf16* __restrict__ Kw, const bf16* __restrict__ Vtw,
    bf16* __restrict__ Opb, float2* __restrict__ ml) {
  __shared__ bf16 Kl[64 * 136];       // [kv][d] pad 128->136
  __shared__ bf16 Vl[128 * 72];       // [d][kv] pad 64->72
  __shared__ bf16 Pl[4 * 32 * 72];    // per-wave [32][72]

  const int t = threadIdx.x;
  const int w = t >> 6;
  const int lane = t & 63;
  const int l15 = lane & 15;
  const int quad = lane >> 4;
  const int qb = blockIdx.x;          // 0..127
  const int sp = blockIdx.y;          // 0..3
  const int batch = qb >> 5;
  const int q0w = qb * 128 + w * 32;
  const int kv_base = batch * 4096 + sp * 1024;

  // Q fragments in registers: A[m=q][k=d]
  bf16x8 qf[2][4];
#pragma unroll
  for (int mt = 0; mt < 2; mt++)
#pragma unroll
    for (int ks = 0; ks < 4; ks++)
      qf[mt][ks] = *(const bf16x8*)&Qw[(size_t)(q0w + mt * 16 + l15) * DDIM + ks * 32 + quad * 8];

  f32x4 zero4 = {0.f, 0.f, 0.f, 0.f};
  f32x4 o[2][8];
#pragma unroll
  for (int mt = 0; mt < 2; mt++)
#pragma unroll
    for (int dt = 0; dt < 8; dt++) o[mt][dt] = zero4;
  float mi[2][4], li[2][4];
#pragma unroll
  for (int mt = 0; mt < 2; mt++)
#pragma unroll
    for (int r = 0; r < 4; r++) { mi[mt][r] = -INFINITY; li[mt][r] = 0.f; }

  bf16* Pw = Pl + w * (32 * 72);
  const int kr = t >> 4;          // K staging row 0..15
  const int kcol = (t & 15) << 3;
  const int vr = t >> 3;          // V staging row 0..31
  const int vcol = (t & 7) << 3;

  bf16x8 ka[4], va[4];
#pragma unroll
  for (int c = 0; c < 4; c++)
    ka[c] = *(const bf16x8*)&Kw[(size_t)(kv_base + c * 16 + kr) * DDIM + kcol];
#pragma unroll
  for (int c = 0; c < 4; c++)
    va[c] = *(const bf16x8*)&Vtw[(size_t)(c * 32 + vr) * LQ + kv_base + vcol];

  for (int tile = 0; tile < 16; tile++) {
    __syncthreads();
#pragma unroll
    for (int c = 0; c < 4; c++)
      *(bf16x8*)&Kl[(c * 16 + kr) * 136 + kcol] = ka[c];
#pragma unroll
    for (int c = 0; c < 4; c++)
      *(bf16x8*)&Vl[(c * 32 + vr) * 72 + vcol] = va[c];
    __syncthreads();

    const int kvn = kv_base + (tile < 15 ? tile + 1 : 15) * 64;  // clamped prefetch
#pragma unroll
    for (int c = 0; c < 4; c++)
      ka[c] = *(const bf16x8*)&Kw[(size_t)(kvn + c * 16 + kr) * DDIM + kcol];
#pragma unroll
    for (int c = 0; c < 4; c++)
      va[c] = *(const bf16x8*)&Vtw[(size_t)(c * 32 + vr) * LQ + kvn + vcol];

    // S = Q K^T  (m=q 32, n=kv 64)
    f32x4 sv[2][4];
#pragma unroll
    for (int mt = 0; mt < 2; mt++)
#pragma unroll
      for (int nt = 0; nt < 4; nt++) sv[mt][nt] = zero4;
#pragma unroll
    for (int ks = 0; ks < 4; ks++) {
      bf16x8 kf[4];
#pragma unroll
      for (int nt = 0; nt < 4; nt++)
        kf[nt] = *(const bf16x8*)&Kl[(nt * 16 + l15) * 136 + ks * 32 + quad * 8];
#pragma unroll
      for (int mt = 0; mt < 2; mt++)
#pragma unroll
        for (int nt = 0; nt < 4; nt++)
          sv[mt][nt] = __builtin_amdgcn_mfma_f32_16x16x32_bf16(qf[mt][ks], kf[nt], sv[mt][nt], 0, 0, 0);
    }
#pragma unroll
    for (int mt = 0; mt < 2; mt++)
#pragma unroll
      for (int nt = 0; nt < 4; nt++) sv[mt][nt] *= SCALE;

    // online softmax; C-layout: row q = mt*16 + quad*4 + r, col kv = nt*16 + l15
#pragma unroll
    for (int mt = 0; mt < 2; mt++) {
#pragma unroll
      for (int r = 0; r < 4; r++) {
        float rm = fmaxf(fmaxf(sv[mt][0][r], sv[mt][1][r]), fmaxf(sv[mt][2][r], sv[mt][3][r]));
#pragma unroll
        for (int msk = 1; msk < 16; msk <<= 1) rm = fmaxf(rm, __shfl_xor(rm, msk));
        float mnew = fmaxf(mi[mt][r], rm);
        float alpha = __expf(mi[mt][r] - mnew);
        mi[mt][r] = mnew;
        float rsum = 0.f;
#pragma unroll
        for (int nt = 0; nt < 4; nt++) {
          float p = __expf(sv[mt][nt][r] - mnew);
          sv[mt][nt][r] = p;
          rsum += p;
        }
#pragma unroll
        for (int msk = 1; msk < 16; msk <<= 1) rsum += __shfl_xor(rsum, msk);
        li[mt][r] = li[mt][r] * alpha + rsum;
#pragma unroll
        for (int dt = 0; dt < 8; dt++) o[mt][dt][r] *= alpha;   // per-row rescale
      }
    }

    // P: C-layout -> A-layout via own-wave LDS region (no barrier needed)
#pragma unroll
    for (int mt = 0; mt < 2; mt++)
#pragma unroll
      for (int nt = 0; nt < 4; nt++)
#pragma unroll
        for (int r = 0; r < 4; r++)
          Pw[(mt * 16 + quad * 4 + r) * 72 + nt * 16 + l15] = (bf16)sv[mt][nt][r];

    // O += P V   (A = P[m=q][k=kv], B = V[k=kv][n=d] from Vt)
#pragma unroll
    for (int ks = 0; ks < 2; ks++) {
      bf16x8 pf[2];
#pragma unroll
      for (int mt = 0; mt < 2; mt++)
        pf[mt] = *(const bf16x8*)&Pw[(mt * 16 + l15) * 72 + ks * 32 + quad * 8];
#pragma unroll
      for (int dt = 0; dt < 8; dt++) {
        bf16x8 vf = *(const bf16x8*)&Vl[(dt * 16 + l15) * 72 + ks * 32 + quad * 8];
#pragma unroll
        for (int mt = 0; mt < 2; mt++)
          o[mt][dt] = __builtin_amdgcn_mfma_f32_16x16x32_bf16(pf[mt], vf, o[mt][dt], 0, 0, 0);
      }
    }
  }

  // epilogue: unnormalized O (bf16) + (m,l)
  const size_t po = (size_t)sp * LQ * DDIM;
#pragma unroll
  for (int mt = 0; mt < 2; mt++)
#pragma unroll
    for (int dt = 0; dt < 8; dt++)
#pragma unroll
      for (int r = 0; r < 4; r++)
        Opb[po + (size_t)(q0w + mt * 16 + quad * 4 + r) * DDIM + dt * 16 + l15] = (bf16)o[mt][dt][r];
  if (l15 == 0) {
#pragma unroll
    for (int mt = 0; mt < 2; mt++)
#pragma unroll
      for (int r = 0; r < 4; r++)
        ml[(size_t)sp * LQ + q0w + mt * 16 + quad * 4 + r] = make_float2(mi[mt][r], li[mt][r]);
  }
}

// ---------------- K3: combine the NSPLIT partials (fp32 out) ------------
__global__ void combine_kernel(const bf16* __restrict__ Opb, const float2* __restrict__ ml,
                               float* __restrict__ out) {
  int idx = blockIdx.x * 256 + threadIdx.x;   // LQ * 32
  int q = idx >> 5;
  int d = (idx & 31) * 4;
  float m[NSPLIT], l[NSPLIT];
  float M = -INFINITY;
#pragma unroll
  for (int sp = 0; sp < NSPLIT; sp++) {
    float2 a = ml[(size_t)sp * LQ + q];
    m[sp] = a.x; l[sp] = a.y;
    M = fmaxf(M, a.x);
  }
  float wsum = 0.f;
  float acc[4] = {0.f, 0.f, 0.f, 0.f};
#pragma unroll
  for (int sp = 0; sp < NSPLIT; sp++) {
    float wgt = __expf(m[sp] - M);
    wsum += wgt * l[sp];
    bf16x4 ov = *(const bf16x4*)&Opb[(size_t)sp * LQ * DDIM + (size_t)q * DDIM + d];
#pragma unroll
    for (int j = 0; j < 4; j++) acc[j] += wgt * (float)ov[j];
  }
  float inv = 1.0f / wsum;
  float4 r;
  r.x = acc[0] * inv; r.y = acc[1] * inv; r.z = acc[2] * inv; r.w = acc[3] * inv;
  *(float4*)&out[(size_t)q * DDIM + d] = r;
}

extern "C" void kernel_launch(void* const* d_in, const int* in_sizes, int n_in,
                              void* d_out, int out_size, void* d_ws, size_t ws_size,
                              hipStream_t stream) {
  const float* x  = (const float*)d_in[0];
  const float* Wq = (const float*)d_in[1];
  const float* bq = (const float*)d_in[2];
  const float* Wk = (const float*)d_in[3];
  const float* bk = (const float*)d_in[4];
  const float* Wv = (const float*)d_in[5];
  const float* bv = (const float*)d_in[6];
  char* ws = (char*)d_ws;
  bf16* Qw  = (bf16*)(ws);                              // 4 MB
  bf16* Kw  = (bf16*)(ws + ((size_t)4 << 20));          // 4 MB
  bf16* Vtw = (bf16*)(ws + ((size_t)8 << 20));          // 4 MB (transposed: [d][q])
  bf16* Wt3 = (bf16*)(ws + ((size_t)12 << 20));         // 768 KB
  bf16* Opb = (bf16*)(ws + ((size_t)12 << 20) + 786432);            // 16 MB (4 splits, bf16)
  float2* mlp = (float2*)(ws + ((size_t)12 << 20) + 786432 + ((size_t)16 << 20)); // 512 KB
  float* out = (float*)d_out;

  wtrans_kernel<<<1536, 256, 0, stream>>>(Wq, Wk, Wv, Wt3);
  qkv_gemm<<<dim3(256, 3), 256, 0, stream>>>(x, Wt3, bq, bk, bv, Qw, Kw, Vtw);
  flash_kernel<<<dim3(128, NSPLIT), 256, 0, stream>>>(Qw, Kw, Vtw, Opb, mlp);
  combine_kernel<<<2048, 256, 0, stream>>>(Opb, mlp, out);
}